// Round 1
// baseline (218.842 us; speedup 1.0000x reference)
//
#include <hip/hip_runtime.h>

#define WS 128
#define HW (1024 * 1024)
#define PLANE 8388608   // C * WS * WS = 512 * 16384
#define PERM_BYTE_OFF 33554432   // perm[] lives after the 32 MB P array in ws

typedef _Float16 half4 __attribute__((ext_vector_type(4)));
typedef _Float16 half8 __attribute__((ext_vector_type(8)));
typedef float floatx4 __attribute__((ext_vector_type(4)));

// interleave 10-bit value with zeros (Morton helper)
__device__ inline unsigned part1by1(unsigned v) {
    v &= 0x0000ffff;
    v = (v ^ (v << 8)) & 0x00ff00ff;
    v = (v ^ (v << 4)) & 0x0f0f0f0f;
    v = (v ^ (v << 2)) & 0x33333333;
    v = (v ^ (v << 1)) & 0x55555555;
    return v;
}

// Kernel A: P[src][j] = sum_e W1[e][j] * xs[e][src]   (window-independent layer-1)
// Stored px-major fp16: P + src*16 + j, so kernel B's B-fragment load is one half4.
// Extra block (blockIdx.x == 4096): rank-sort the 512 centroids by Morton code of
// their clamped centres -> perm[], so kernel B can process spatially adjacent
// windows on the same XCD (L2 locality for the 8x-overlapping P gather).
__global__ __launch_bounds__(256) void precompute_P(
    const float* __restrict__ x,      // (6, 1024, 1024)
    const float* __restrict__ sigma,  // (1, 1024, 1024)
    const float* __restrict__ W1,     // (7, 16)
    const int*   __restrict__ cent,   // (512, 2)
    _Float16* __restrict__ P,         // (1024*1024, 16)
    int* __restrict__ perm)           // (512)
{
    if (blockIdx.x == 4096) {
        __shared__ unsigned keys[512];
        const int t = threadIdx.x;
        for (int i = t; i < 512; i += 256) {
            const unsigned cy = (unsigned)min(max(cent[2 * i], 64), 960);
            const unsigned cx = (unsigned)min(max(cent[2 * i + 1], 64), 960);
            keys[i] = (part1by1(cy) << 1) | part1by1(cx);
        }
        __syncthreads();
        for (int i = t; i < 512; i += 256) {
            const unsigned ki = keys[i];
            int r = 0;
            for (int j = 0; j < 512; ++j) {
                const unsigned kj = keys[j];
                r += (kj < ki || (kj == ki && j < i)) ? 1 : 0;
            }
            perm[r] = i;   // bijection: every rank hit exactly once
        }
        return;
    }

    const int px = blockIdx.x * 256 + threadIdx.x;
    float g[7];
#pragma unroll
    for (int e = 0; e < 6; ++e) g[e] = x[e * HW + px];
    g[6] = sigma[px];

    half8 lo, hi;
#pragma unroll
    for (int j = 0; j < 16; ++j) {
        float a = 0.0f;
#pragma unroll
        for (int e = 0; e < 7; ++e)
            a = fmaf(g[e], W1[e * 16 + j], a);
        if (j < 8) lo[j] = (_Float16)a; else hi[j - 8] = (_Float16)a;
    }
    *(half8*)(P + (size_t)px * 16)     = lo;
    *(half8*)(P + (size_t)px * 16 + 8) = hi;
}

// Kernel B: per window-pixel  h1 = relu(P[src] - q[cid]);  h2 = relu(W2^T h1 + b2);
//           prob = sigmoid(W3 . h2 + b3).  Layer 2 on the matrix pipe.
// 1-D grid, decoded so XCD (= lid & 7 under the measured round-robin mapping) g
// processes whole windows of ranks [64g, 64g+64) in sliding Morton order:
// concurrent windows per XCD are spatially adjacent -> P gather hits its 4 MiB L2.
__global__ __launch_bounds__(256) void instanseg_mlp(
    const _Float16* __restrict__ P,   // (1024*1024, 16)
    const float* __restrict__ c,      // (512, 6)
    const float* __restrict__ W1,     // (7, 16)
    const float* __restrict__ b1,     // (16)
    const float* __restrict__ W2,     // (16, 16)
    const float* __restrict__ b2,     // (16)
    const float* __restrict__ W3,     // (16, 1)
    const float* __restrict__ b3,     // (1)
    const int*   __restrict__ cent,   // (512, 2)
    const int*   __restrict__ perm,   // (512) Morton-rank -> cid
    float* __restrict__ out)
{
    const int lid   = blockIdx.x;
    const int g     = lid & 7;        // XCD under lid%8 round-robin
    const int jj    = lid >> 3;       // [0,512): temporal order within XCD
    const int rank  = g * 64 + (jj >> 3);
    const int chunk = jj & 7;
    const int cid   = perm[rank];

    const int lane = threadIdx.x & 63;
    const int wave = threadIdx.x >> 6;
    const int quad = lane >> 4;
    const int sub  = lane & 15;

    const int cy = min(max(cent[2 * cid], 64), 960);
    const int cx = min(max(cent[2 * cid + 1], 64), 960);
    const int cy0 = cy - 64, cx0 = cx - 64;

    // A-fragment for layer 2: A[m=sub][k=4*quad+i] = W2[k][m]
    half4 a2;
    float w3f[4], bb2[4];
    half4 qh;   // q[k] = sum_{e<6} W1[e][k]*c[cid][e] - b1[k], k = 4*quad+i
#pragma unroll
    for (int i = 0; i < 4; ++i) {
        const int k = 4 * quad + i;
        a2[i]  = (_Float16)W2[k * 16 + sub];
        w3f[i] = W3[k];
        bb2[i] = b2[k];
        float qv = -b1[k];
#pragma unroll
        for (int e = 0; e < 6; ++e)
            qv = fmaf(W1[e * 16 + k], c[cid * 6 + e], qv);
        qh[i] = (_Float16)qv;
    }
    const float b3v = b3[0];
    const floatx4 zero = {0.0f, 0.0f, 0.0f, 0.0f};

    const int wavestart = chunk * 2048 + wave * 512;

    for (int it = 0; it < 8; ++it) {
        const int start = wavestart + it * 64;
        float logit[4];
#pragma unroll
        for (int ch = 0; ch < 4; ++ch) {
            const int gp  = start + ch * 16 + sub;
            const int src = (cy0 + (gp >> 7)) * 1024 + cx0 + (gp & 127);

            // B-fragment: channels 4q..4q+3 of pixel sub — one contiguous 8B load
            half4 v = *(const half4*)(P + (size_t)src * 16 + quad * 4);
            half4 h = v - qh;                       // v_pk_add_f16
#pragma unroll
            for (int i = 0; i < 4; ++i)             // relu -> v_pk_max_f16
                h[i] = h[i] > (_Float16)0.0f ? h[i] : (_Float16)0.0f;

            floatx4 c2 = __builtin_amdgcn_mfma_f32_16x16x16f16(a2, h, zero, 0, 0, 0);

            float part = 0.0f;
#pragma unroll
            for (int i = 0; i < 4; ++i)
                part = fmaf(w3f[i], fmaxf(c2[i] + bb2[i], 0.0f), part);
            part += __shfl_xor(part, 16, 64);
            part += __shfl_xor(part, 32, 64);
            logit[ch] = part;
        }

        const float l01 = (quad & 1) ? logit[1] : logit[0];
        const float l23 = (quad & 1) ? logit[3] : logit[2];
        const float lg  = (quad & 2) ? l23 : l01;
        const float prob = 1.0f / (1.0f + __expf(-(lg + b3v)));

        const int gps = start + lane;
        const int n   = cid * 16384 + gps;
        out[n]             = prob;
        out[PLANE + n]     = (float)cid;
        out[2 * PLANE + n] = (float)(cy0 + (gps >> 7));
        out[3 * PLANE + n] = (float)(cx0 + (gps & 127));
    }
}

extern "C" void kernel_launch(void* const* d_in, const int* in_sizes, int n_in,
                              void* d_out, int out_size, void* d_ws, size_t ws_size,
                              hipStream_t stream) {
    const float* x     = (const float*)d_in[0];
    const float* sigma = (const float*)d_in[1];
    const float* c     = (const float*)d_in[2];
    const float* W1    = (const float*)d_in[3];
    const float* b1    = (const float*)d_in[4];
    const float* W2    = (const float*)d_in[5];
    const float* b2    = (const float*)d_in[6];
    const float* W3    = (const float*)d_in[7];
    const float* b3    = (const float*)d_in[8];
    const int*   cent  = (const int*)d_in[9];
    float* out = (float*)d_out;
    _Float16* P = (_Float16*)d_ws;                          // 32 MB fp16 scratch
    int* perm   = (int*)((char*)d_ws + PERM_BYTE_OFF);      // 2 KB after P

    precompute_P<<<dim3(4097), dim3(256), 0, stream>>>(x, sigma, W1, cent, P, perm);
    instanseg_mlp<<<dim3(4096), dim3(256), 0, stream>>>(
        P, c, W1, b1, W2, b2, W3, b3, cent, perm, out);
}

// Round 2
// 214.768 us; speedup vs baseline: 1.0190x; 1.0190x over previous
//
#include <hip/hip_runtime.h>

#define WS 128
#define HW (1024 * 1024)
#define PLANE 8388608   // C * WS * WS = 512 * 16384

typedef _Float16 half4 __attribute__((ext_vector_type(4)));
typedef _Float16 half8 __attribute__((ext_vector_type(8)));
typedef float floatx4 __attribute__((ext_vector_type(4)));

// Kernel A: P[src][j] = sum_e W1[e][j] * xs[e][src]   (window-independent layer-1)
// Stored px-major fp16: P + src*16 + j, so kernel B's B-fragment load is one half4.
__global__ __launch_bounds__(256) void precompute_P(
    const float* __restrict__ x,      // (6, 1024, 1024)
    const float* __restrict__ sigma,  // (1, 1024, 1024)
    const float* __restrict__ W1,     // (7, 16)
    _Float16* __restrict__ P)         // (1024*1024, 16)
{
    const int px = blockIdx.x * 256 + threadIdx.x;
    float g[7];
#pragma unroll
    for (int e = 0; e < 6; ++e) g[e] = x[e * HW + px];
    g[6] = sigma[px];

    half8 lo, hi;
#pragma unroll
    for (int j = 0; j < 16; ++j) {
        float a = 0.0f;
#pragma unroll
        for (int e = 0; e < 7; ++e)
            a = fmaf(g[e], W1[e * 16 + j], a);
        if (j < 8) lo[j] = (_Float16)a; else hi[j - 8] = (_Float16)a;
    }
    *(half8*)(P + (size_t)px * 16)     = lo;
    *(half8*)(P + (size_t)px * 16 + 8) = hi;
}

// Kernel B: per window-pixel  h1 = relu(P[src] - q[cid]);  h2 = relu(W2^T h1 + b2);
//           prob = sigmoid(W3 . h2 + b3).  Layer 2 on the matrix pipe.
// Round-2 changes: (a) 2-stage software pipeline — the 4 B-fragment gathers of
// iteration it+1 are issued as a batch while iteration it computes, so 8 loads
// (4 KB/wave) stay in flight instead of ~1 (B was LLC-latency-bound, not BW-bound);
// (b) row-base addressing: each wave-iter's 64 px lie in ONE image row, so one
// base register + ch*512B immediate offsets replace per-ch address chains, and
// row/cid store values become wave-uniform; (c) nontemporal stores for the 134 MB
// write-only out stream (keep L2 for the P gather).
__global__ __launch_bounds__(256) void instanseg_mlp(
    const _Float16* __restrict__ P,   // (1024*1024, 16)
    const float* __restrict__ c,      // (512, 6)
    const float* __restrict__ W1,     // (7, 16)
    const float* __restrict__ b1,     // (16)
    const float* __restrict__ W2,     // (16, 16)
    const float* __restrict__ b2,     // (16)
    const float* __restrict__ W3,     // (16, 1)
    const float* __restrict__ b3,     // (1)
    const int*   __restrict__ cent,   // (512, 2)
    float* __restrict__ out)
{
    const int cid  = blockIdx.y;
    const int lane = threadIdx.x & 63;
    const int wave = threadIdx.x >> 6;
    const int quad = lane >> 4;
    const int sub  = lane & 15;

    const int cy = min(max(cent[2 * cid], 64), 960);
    const int cx = min(max(cent[2 * cid + 1], 64), 960);
    const int cy0 = cy - 64, cx0 = cx - 64;

    // A-fragment for layer 2: A[m=sub][k=4*quad+i] = W2[k][m]
    half4 a2;
    float w3f[4], bb2[4];
    half4 qh;   // q[k] = sum_{e<6} W1[e][k]*c[cid][e] - b1[k], k = 4*quad+i
#pragma unroll
    for (int i = 0; i < 4; ++i) {
        const int k = 4 * quad + i;
        a2[i]  = (_Float16)W2[k * 16 + sub];
        w3f[i] = W3[k];
        bb2[i] = b2[k];
        float qv = -b1[k];
#pragma unroll
        for (int e = 0; e < 6; ++e)
            qv = fmaf(W1[e * 16 + k], c[cid * 6 + e], qv);
        qh[i] = (_Float16)qv;
    }
    const float b3v = b3[0];
    const floatx4 zero = {0.0f, 0.0f, 0.0f, 0.0f};

    const int wavestart = blockIdx.x * 2048 + wave * 512;

    // ---- 2-stage pipelined gather + compute over 8 wave-iterations ----
    half4 v[4], vn[4];
    {
        // wavestart is a multiple of 512 -> (wavestart & 127) == 0; all 64 px of
        // a wave-iteration are one contiguous row segment.
        const int base = (cy0 + (wavestart >> 7)) * 1024 + cx0 + sub;
        const _Float16* rowp = P + (size_t)base * 16 + quad * 4;
#pragma unroll
        for (int ch = 0; ch < 4; ++ch)
            v[ch] = *(const half4*)(rowp + ch * 256);   // ch*16 px * 16ch = 512 B
    }

    for (int it = 0; it < 8; ++it) {
        const int start = wavestart + it * 64;

        if (it < 7) {   // batch-issue next iteration's 4 gathers
            const int nstart = start + 64;
            const int base = (cy0 + (nstart >> 7)) * 1024 + cx0 + (nstart & 127) + sub;
            const _Float16* rowp = P + (size_t)base * 16 + quad * 4;
#pragma unroll
            for (int ch = 0; ch < 4; ++ch)
                vn[ch] = *(const half4*)(rowp + ch * 256);
        }

        float logit[4];
#pragma unroll
        for (int ch = 0; ch < 4; ++ch) {
            half4 h = v[ch] - qh;                       // v_pk_add_f16
#pragma unroll
            for (int i = 0; i < 4; ++i)                 // relu -> v_pk_max_f16
                h[i] = h[i] > (_Float16)0.0f ? h[i] : (_Float16)0.0f;

            floatx4 c2 = __builtin_amdgcn_mfma_f32_16x16x16f16(a2, h, zero, 0, 0, 0);

            float part = 0.0f;
#pragma unroll
            for (int i = 0; i < 4; ++i)
                part = fmaf(w3f[i], fmaxf(c2[i] + bb2[i], 0.0f), part);
            part += __shfl_xor(part, 16, 64);
            part += __shfl_xor(part, 32, 64);
            logit[ch] = part;
        }

        const float l01 = (quad & 1) ? logit[1] : logit[0];
        const float l23 = (quad & 1) ? logit[3] : logit[2];
        const float lg  = (quad & 2) ? l23 : l01;
        const float prob = 1.0f / (1.0f + __expf(-(lg + b3v)));

        const int rowy = cy0 + (start >> 7);            // wave-uniform
        const int colx = cx0 + (start & 127) + lane;
        const int n    = cid * 16384 + start + lane;
        __builtin_nontemporal_store(prob,        out + n);
        __builtin_nontemporal_store((float)cid,  out + PLANE + n);
        __builtin_nontemporal_store((float)rowy, out + 2 * PLANE + n);
        __builtin_nontemporal_store((float)colx, out + 3 * PLANE + n);

        if (it < 7) {
#pragma unroll
            for (int ch = 0; ch < 4; ++ch) v[ch] = vn[ch];
        }
    }
}

extern "C" void kernel_launch(void* const* d_in, const int* in_sizes, int n_in,
                              void* d_out, int out_size, void* d_ws, size_t ws_size,
                              hipStream_t stream) {
    const float* x     = (const float*)d_in[0];
    const float* sigma = (const float*)d_in[1];
    const float* c     = (const float*)d_in[2];
    const float* W1    = (const float*)d_in[3];
    const float* b1    = (const float*)d_in[4];
    const float* W2    = (const float*)d_in[5];
    const float* b2    = (const float*)d_in[6];
    const float* W3    = (const float*)d_in[7];
    const float* b3    = (const float*)d_in[8];
    const int*   cent  = (const int*)d_in[9];
    float* out = (float*)d_out;
    _Float16* P = (_Float16*)d_ws;   // 1024*1024*16 fp16 = 32 MB scratch

    precompute_P<<<dim3(HW / 256), dim3(256), 0, stream>>>(x, sigma, W1, P);
    instanseg_mlp<<<dim3(8, 512), dim3(256), 0, stream>>>(
        P, c, W1, b1, W2, b2, W3, b3, cent, out);
}